// Round 13
// baseline (180.698 us; speedup 1.0000x reference)
//
#include <hip/hip_runtime.h>

// ---------------- constants for this problem ----------------
// N_NODES=100000, N_EDGES=1600000, IN_FEATS=128, H=4, D=32, HD=128, NUM_ETYPES=8, DROP_BLOCKS=4
// Bucket = 512 consecutive dst nodes (nbuk = ceil(N/512) = 196).
// csr2 entry: src[0:17) | etype[17:20) | (dst&511)[20:29)
// csr  entry: src[0:20) | etype[20:23)

typedef short short8 __attribute__((ext_vector_type(8)));
typedef unsigned short ushort8 __attribute__((ext_vector_type(8)));
typedef float f32x4 __attribute__((ext_vector_type(4)));

__device__ inline unsigned short f2bf(float x) {
    unsigned u = __builtin_bit_cast(unsigned, x);
    u += 0x7FFFu + ((u >> 16) & 1u);   // RNE
    return (unsigned short)(u >> 16);
}

__device__ inline short8 cvt8(float4 lo, float4 hi) {
    short8 t;
    t[0] = (short)f2bf(lo.x); t[1] = (short)f2bf(lo.y);
    t[2] = (short)f2bf(lo.z); t[3] = (short)f2bf(lo.w);
    t[4] = (short)f2bf(hi.x); t[5] = (short)f2bf(hi.y);
    t[6] = (short)f2bf(hi.z); t[7] = (short)f2bf(hi.w);
    return t;
}

__device__ inline void nt_store4(float* p, float a, float b, float c, float d) {
    f32x4 v = (f32x4){a, b, c, d};
    __builtin_nontemporal_store(v, (f32x4*)p);
}

// K1: per-chunk bucket histogram (non-atomic partials, no memset needed).
// Blocks 0..7 additionally convert W (16384 fp32) -> Wb bf16.
__global__ __launch_bounds__(256) void k_bcnt(const int* __restrict__ dst,
                                              unsigned* __restrict__ gpart, int E,
                                              const float* __restrict__ W,
                                              unsigned short* __restrict__ Wb) {
    __shared__ unsigned l[256];
    int tid = threadIdx.x;
    if (blockIdx.x < 8) {
        int i = blockIdx.x * 2048 + tid * 8;
        float4 lo = *(const float4*)(W + i);
        float4 hi = *(const float4*)(W + i + 4);
        *(ushort8*)(Wb + i) = __builtin_bit_cast(ushort8, cvt8(lo, hi));
    }
    l[tid] = 0;
    __syncthreads();
    int base = blockIdx.x * 4096;
#pragma unroll
    for (int j = 0; j < 16; ++j) {
        int e = base + j * 256 + tid;
        if (e < E) atomicAdd(&l[(unsigned)dst[e] >> 9], 1u);
    }
    __syncthreads();
    gpart[blockIdx.x * 256 + tid] = l[tid];
}

// K2: column-reduce partials + exclusive scan (single block)
__global__ __launch_bounds__(256) void k_bscan(const unsigned* __restrict__ gpart,
                                               int nchunk,
                                               unsigned* __restrict__ gbase,
                                               unsigned* __restrict__ gcur) {
    __shared__ unsigned s[256];
    int t = threadIdx.x;
    unsigned sum = 0;
    int r = 0;
    for (; r + 4 <= nchunk; r += 4) {
        unsigned a0 = gpart[(r + 0) * 256 + t];
        unsigned a1 = gpart[(r + 1) * 256 + t];
        unsigned a2 = gpart[(r + 2) * 256 + t];
        unsigned a3 = gpart[(r + 3) * 256 + t];
        sum += a0 + a1 + a2 + a3;
    }
    for (; r < nchunk; ++r) sum += gpart[r * 256 + t];
    unsigned orig = sum;
    s[t] = sum;
    __syncthreads();
    for (int of = 1; of < 256; of <<= 1) {
        unsigned v = (t >= of) ? s[t - of] : 0u;
        __syncthreads();
        s[t] += v;
        __syncthreads();
    }
    unsigned eb = s[t] - orig;
    gbase[t] = eb;
    gcur[t] = eb;
}

// K3 (FUSED, role-interleaved): bid%3==2 -> partition (rid=bid/3);
// else GEMM (rid=(bid/3)*2 + bid%3). Ratio gemm:part = 2:1 exactly.
__global__ __launch_bounds__(256) void k_partgemm(
        const int* __restrict__ src, const int* __restrict__ dst,
        const int* __restrict__ ef, unsigned* __restrict__ gcur,
        unsigned* __restrict__ csr2, int E, int nbuk,
        const float* __restrict__ feat, const unsigned short* __restrict__ Wb,
        unsigned short* __restrict__ ftb, int N) {
    __shared__ unsigned short Sb[128 * 136];  // 34 KB union
    int tid = threadIdx.x;
    int bid = blockIdx.x;
    int r3 = bid % 3, q3 = bid / 3;

    if (r3 == 2) {
        // ---------------- partition path ----------------
        unsigned* lcnt = (unsigned*)Sb;
        unsigned* lbase = lcnt + 256;
        unsigned* lcur = lbase + 256;
        unsigned* gw2 = lcur + 256;
        unsigned* stp = gw2 + 256;
        unsigned short* stb = (unsigned short*)(stp + 4096);
        lcnt[tid] = 0;
        __syncthreads();

        int cb = q3 * 4096;
        int cc = E - cb; if (cc > 4096) cc = 4096;

        unsigned pay[16];
        unsigned short bk[16];
#pragma unroll
        for (int j = 0; j < 16; ++j) {
            int idx = j * 256 + tid;
            if (idx < cc) {
                int e = cb + idx;
                unsigned d = (unsigned)dst[e];
                pay[j] = (unsigned)src[e] | ((unsigned)ef[e] << 17) | ((d & 511u) << 20);
                bk[j] = (unsigned short)(d >> 9);
                atomicAdd(&lcnt[bk[j]], 1u);
            }
        }
        __syncthreads();
        lbase[tid] = lcnt[tid];
        __syncthreads();
        for (int of = 1; of < 256; of <<= 1) {
            unsigned v = (tid >= of) ? lbase[tid - of] : 0u;
            __syncthreads();
            lbase[tid] += v;
            __syncthreads();
        }
        unsigned eb = lbase[tid] - lcnt[tid];
        __syncthreads();
        lbase[tid] = eb;
        lcur[tid] = eb;
        __syncthreads();
#pragma unroll
        for (int j = 0; j < 16; ++j) {
            int idx = j * 256 + tid;
            if (idx < cc) {
                unsigned lpos = atomicAdd(&lcur[bk[j]], 1u);
                stp[lpos] = pay[j];
                stb[lpos] = bk[j];
            }
        }
        if (tid < nbuk && lcnt[tid]) gw2[tid] = atomicAdd(&gcur[tid], lcnt[tid]);
        __syncthreads();
#pragma unroll
        for (int j = 0; j < 16; ++j) {
            int i = j * 256 + tid;
            if (i < cc) {
                unsigned b = stb[i];
                csr2[gw2[b] + (i - lbase[b])] = stp[i];
            }
        }
        return;
    }

    // ---------------- GEMM path (register-pipelined) ----------------
    int row0 = (q3 * 2 + r3) * 128;

#pragma unroll
    for (int it = 0; it < 8; ++it) {
        int idx = it * 2048 + tid * 8;
        int r = idx >> 7, c = idx & 127;
        ushort8 v = *(const ushort8*)(Wb + idx);
        *(ushort8*)((char*)Sb + (((unsigned)(r * 256 + c * 2)) ^ (unsigned)((r & 7) << 4))) = v;
    }
    __syncthreads();

    int wv = tid >> 6, lane = tid & 63;
    int rl = lane & 15;
    unsigned swz = (unsigned)((lane & 7) << 4);
    int kq = (lane >> 4) * 16;
    int ko = (lane >> 4) * 8;

    int ra0 = row0 + wv * 32 + rl;
    int ra1 = ra0 + 16;
    int rc0 = ra0 < N - 1 ? ra0 : N - 1;
    int rc1 = ra1 < N - 1 ? ra1 : N - 1;
    const float* ap0 = feat + (size_t)rc0 * 128 + ko;
    const float* ap1 = feat + (size_t)rc1 * 128 + ko;

    f32x4 acc[2][8];
#pragma unroll
    for (int rt = 0; rt < 2; ++rt)
#pragma unroll
        for (int jt = 0; jt < 8; ++jt)
            acc[rt][jt] = (f32x4){0.f, 0.f, 0.f, 0.f};

    const char* Bb = (const char*)Sb;

    float4 l0 = *(const float4*)(ap0);
    float4 h0 = *(const float4*)(ap0 + 4);
    float4 l1 = *(const float4*)(ap1);
    float4 h1 = *(const float4*)(ap1 + 4);

#pragma unroll 1
    for (int kk = 0; kk < 4; ++kk) {
        short8 a0 = cvt8(l0, h0);
        short8 a1 = cvt8(l1, h1);
        int kn = kk < 3 ? kk + 1 : 3;
        l0 = *(const float4*)(ap0 + kn * 32);
        h0 = *(const float4*)(ap0 + kn * 32 + 4);
        l1 = *(const float4*)(ap1 + kn * 32);
        h1 = *(const float4*)(ap1 + kn * 32 + 4);
        int kb = kk * 64 + kq;
#pragma unroll
        for (int jt = 0; jt < 8; ++jt) {
            short8 bj = *(const short8*)(Bb + (((unsigned)((jt * 16 + rl) * 256 + kb)) ^ swz));
            acc[0][jt] = __builtin_amdgcn_mfma_f32_16x16x32_bf16(a0, bj, acc[0][jt], 0, 0, 0);
            acc[1][jt] = __builtin_amdgcn_mfma_f32_16x16x32_bf16(a1, bj, acc[1][jt], 0, 0, 0);
        }
    }

    __syncthreads();
#pragma unroll
    for (int rt = 0; rt < 2; ++rt) {
        int rbase = wv * 32 + rt * 16 + ((lane >> 4) << 2);
#pragma unroll
        for (int jt = 0; jt < 8; ++jt) {
            int col = jt * 16 + rl;
#pragma unroll
            for (int rg = 0; rg < 4; ++rg)
                Sb[(rbase + rg) * 136 + col] = f2bf(acc[rt][jt][rg]);
        }
    }
    __syncthreads();
#pragma unroll
    for (int g = 0; g < 8; ++g) {
        int rloc = g * 16 + (tid >> 4);
        int cc = (tid & 15) * 8;
        int gr = row0 + rloc;
        if (gr < N) {
            ushort8 v = *(const ushort8*)(&Sb[rloc * 136 + cc]);
            *(ushort8*)(ftb + (size_t)gr * 128 + cc) = v;
        }
    }
}

// K4: per-bucket: count (node,etype), scan node degrees -> offs/deg/stats,
// then counting-sort into final node-grouped CSR. gend[b] = bucket END index.
__global__ __launch_bounds__(256) void k_bsort2(const unsigned* __restrict__ csr2,
                                                const unsigned* __restrict__ gbase,
                                                const unsigned* __restrict__ gend,
                                                const float* __restrict__ emb,
                                                unsigned* __restrict__ csr,
                                                unsigned* __restrict__ offs,
                                                unsigned* __restrict__ deg,
                                                float* __restrict__ stats, int N) {
    __shared__ unsigned cnt8[512 * 8];   // 16 KB
    __shared__ unsigned degL[512];
    __shared__ unsigned offsL[512];
    __shared__ unsigned curL[512];
    __shared__ unsigned tmp[256];
    __shared__ float se[32];
    int b = blockIdx.x, tid = threadIdx.x;
    if (tid < 32) se[tid] = emb[tid];
#pragma unroll
    for (int i = 0; i < 16; ++i) cnt8[i * 256 + tid] = 0u;
    __syncthreads();
    unsigned r0 = gbase[b], r1 = gend[b];
    for (unsigned i = r0 + tid; i < r1; i += 256) {
        unsigned en = csr2[i];
        atomicAdd(&cnt8[((en >> 20) & 511u) * 8u + ((en >> 17) & 7u)], 1u);
    }
    __syncthreads();
    int n0 = tid * 2, n1 = tid * 2 + 1;
    unsigned d0 = 0, d1 = 0;
#pragma unroll
    for (int k = 0; k < 8; ++k) { d0 += cnt8[n0 * 8 + k]; d1 += cnt8[n1 * 8 + k]; }
    degL[n0] = d0; degL[n1] = d1;
    tmp[tid] = d0 + d1;
    __syncthreads();
    for (int of = 1; of < 256; of <<= 1) {
        unsigned v = (tid >= of) ? tmp[tid - of] : 0u;
        __syncthreads();
        tmp[tid] += v;
        __syncthreads();
    }
    unsigned eb = tmp[tid] - (d0 + d1);
    offsL[n0] = eb;        curL[n0] = eb;
    offsL[n1] = eb + d0;   curL[n1] = eb + d0;
#pragma unroll
    for (int q = 0; q < 2; ++q) {
        int nl = tid * 2 + q;
        int gn = b * 512 + nl;
        if (gn < N) {
            offs[gn] = r0 + offsL[nl];
            unsigned dg = degL[nl];
            deg[gn] = dg;
            const unsigned* c = &cnt8[nl * 8];
#pragma unroll
            for (int h = 0; h < 4; ++h) {
                float m = -3.4e38f;
#pragma unroll
                for (int tt = 0; tt < 8; ++tt)
                    if (c[tt]) m = fmaxf(m, se[tt * 4 + h]);
                float s = 0.f;
#pragma unroll
                for (int tt = 0; tt < 8; ++tt)
                    if (c[tt]) s += (float)c[tt] * expf(se[tt * 4 + h] - m);
                stats[(size_t)gn * 8 + h] = m;
                stats[(size_t)gn * 8 + 4 + h] = dg ? (1.0f / s) : 0.0f;
            }
        }
    }
    __syncthreads();
    for (unsigned i = r0 + tid; i < r1; i += 256) {
        unsigned en = csr2[i];
        unsigned nlo = (en >> 20) & 511u;
        unsigned tt = (en >> 17) & 7u;
        unsigned pos = r0 + atomicAdd(&curL[nlo], 1u);
        csr[pos] = (en & 0x1FFFFu) | (tt << 20);
    }
}

// K5 (FUSED, role-interleaved): bid%5==4 -> attn (rid=bid/5);
// else agg (rid=(bid/5)*4 + bid%5). Ratio agg:attn = 4:1 exactly.
__global__ __launch_bounds__(256) void k_aggattn(
        const unsigned* __restrict__ csr, const unsigned* __restrict__ offs,
        const unsigned* __restrict__ deg, const float* __restrict__ stats,
        const float* __restrict__ emb, const uint4* __restrict__ ft4,
        float* __restrict__ rst, int N,
        const int* __restrict__ e_feat, const int* __restrict__ dst,
        float* __restrict__ ao, int E) {
    __shared__ float sbuf[4 * 257];
    int tid = threadIdx.x;
    int bid = blockIdx.x;
    int r5 = bid % 5, q5 = bid / 5;

    if (r5 == 4) {
        // ---------------- attn_out path ----------------
        int e = q5 * 256 + tid;
        float a0 = 0.f, a1 = 0.f, a2 = 0.f, a3 = 0.f;
        if (e < E) {
            int tt = e_feat[e];
            int d = dst[e];
            const float4* st4 = (const float4*)(stats + (size_t)d * 8);
            float4 m4 = st4[0], i4 = st4[1];
            float4 ee = *(const float4*)(emb + tt * 4);
            a0 = expf(ee.x - m4.x) * i4.x;
            a1 = expf(ee.y - m4.y) * i4.y;
            a2 = expf(ee.z - m4.z) * i4.z;
            a3 = expf(ee.w - m4.w) * i4.w;
        }
        sbuf[0 * 257 + tid] = a0;
        sbuf[1 * 257 + tid] = a1;
        sbuf[2 * 257 + tid] = a2;
        sbuf[3 * 257 + tid] = a3;
        __syncthreads();
        size_t base = (size_t)q5 * 1024;   // float4 index
        size_t lim = (size_t)E * 4;
#pragma unroll
        for (int r = 0; r < 4; ++r) {
            size_t g = base + r * 256 + tid;
            if (g < lim) {
                int gl = r * 256 + tid;
                float v = sbuf[(gl & 3) * 257 + (gl >> 2)];
                nt_store4(ao + g * 4, v, v, v, v);
            }
        }
        return;
    }

    // ---------------- aggregate path ----------------
    float* wl = sbuf;
    int wv = tid >> 6, lane = tid & 63;
    int rid = q5 * 4 + r5;
    int n = rid * 4 + wv;
    n = __builtin_amdgcn_readfirstlane(n);
    if (n < N && lane < 32) {
        int tt = lane >> 2, hh = lane & 3;
        float m = stats[(size_t)n * 8 + hh];
        float is = stats[(size_t)n * 8 + 4 + hh];
        wl[wv * 32 + lane] = expf(emb[tt * 4 + hh] - m) * is;
    }
    __syncthreads();
    if (n >= N) return;
    unsigned o = offs[n], dg = deg[n];
    int cl = lane & 15;
    int es = lane >> 4;
    int h = cl >> 2;
    const float* wlh = wl + wv * 32 + h;
    float acc[8];
#pragma unroll
    for (int i = 0; i < 8; ++i) acc[i] = 0.f;

    for (unsigned kb = 0; kb < dg; kb += 64) {
        unsigned rem = dg - kb; if (rem > 64) rem = 64;
        unsigned centry = 0;
        if (lane < (int)rem) centry = csr[o + kb + lane];
        unsigned g = 0;
        for (; g + 32 <= rem; g += 32) {
            uint4 f[8]; float a[8];
#pragma unroll
            for (int q = 0; q < 8; ++q) {
                unsigned e = __shfl(centry, (int)(g + q * 4 + es), 64);
                f[q] = ft4[(size_t)(e & 0xFFFFFu) * 16 + cl];
                a[q] = wlh[(e >> 20) * 4];
            }
#pragma unroll
            for (int q = 0; q < 8; ++q) {
                acc[0] = fmaf(a[q], __builtin_bit_cast(float, f[q].x << 16), acc[0]);
                acc[1] = fmaf(a[q], __builtin_bit_cast(float, f[q].x & 0xFFFF0000u), acc[1]);
                acc[2] = fmaf(a[q], __builtin_bit_cast(float, f[q].y << 16), acc[2]);
                acc[3] = fmaf(a[q], __builtin_bit_cast(float, f[q].y & 0xFFFF0000u), acc[3]);
                acc[4] = fmaf(a[q], __builtin_bit_cast(float, f[q].z << 16), acc[4]);
                acc[5] = fmaf(a[q], __builtin_bit_cast(float, f[q].z & 0xFFFF0000u), acc[5]);
                acc[6] = fmaf(a[q], __builtin_bit_cast(float, f[q].w << 16), acc[6]);
                acc[7] = fmaf(a[q], __builtin_bit_cast(float, f[q].w & 0xFFFF0000u), acc[7]);
            }
        }
        for (; g + 16 <= rem; g += 16) {
            uint4 f[4]; float a[4];
#pragma unroll
            for (int q = 0; q < 4; ++q) {
                unsigned e = __shfl(centry, (int)(g + q * 4 + es), 64);
                f[q] = ft4[(size_t)(e & 0xFFFFFu) * 16 + cl];
                a[q] = wlh[(e >> 20) * 4];
            }
#pragma unroll
            for (int q = 0; q < 4; ++q) {
                acc[0] = fmaf(a[q], __builtin_bit_cast(float, f[q].x << 16), acc[0]);
                acc[1] = fmaf(a[q], __builtin_bit_cast(float, f[q].x & 0xFFFF0000u), acc[1]);
                acc[2] = fmaf(a[q], __builtin_bit_cast(float, f[q].y << 16), acc[2]);
                acc[3] = fmaf(a[q], __builtin_bit_cast(float, f[q].y & 0xFFFF0000u), acc[3]);
                acc[4] = fmaf(a[q], __builtin_bit_cast(float, f[q].z << 16), acc[4]);
                acc[5] = fmaf(a[q], __builtin_bit_cast(float, f[q].z & 0xFFFF0000u), acc[5]);
                acc[6] = fmaf(a[q], __builtin_bit_cast(float, f[q].w << 16), acc[6]);
                acc[7] = fmaf(a[q], __builtin_bit_cast(float, f[q].w & 0xFFFF0000u), acc[7]);
            }
        }
        for (; g < rem; g += 4) {
            int eidx = (int)g + es;
            bool valid = eidx < (int)rem;
            unsigned e = __shfl(centry, valid ? eidx : (int)g, 64);
            uint4 f = ft4[(size_t)(e & 0xFFFFFu) * 16 + cl];
            float a = valid ? wlh[(e >> 20) * 4] : 0.f;
            acc[0] = fmaf(a, __builtin_bit_cast(float, f.x << 16), acc[0]);
            acc[1] = fmaf(a, __builtin_bit_cast(float, f.x & 0xFFFF0000u), acc[1]);
            acc[2] = fmaf(a, __builtin_bit_cast(float, f.y << 16), acc[2]);
            acc[3] = fmaf(a, __builtin_bit_cast(float, f.y & 0xFFFF0000u), acc[3]);
            acc[4] = fmaf(a, __builtin_bit_cast(float, f.z << 16), acc[4]);
            acc[5] = fmaf(a, __builtin_bit_cast(float, f.z & 0xFFFF0000u), acc[5]);
            acc[6] = fmaf(a, __builtin_bit_cast(float, f.w << 16), acc[6]);
            acc[7] = fmaf(a, __builtin_bit_cast(float, f.w & 0xFFFF0000u), acc[7]);
        }
    }
#pragma unroll
    for (int i = 0; i < 8; ++i) {
        acc[i] += __shfl_xor(acc[i], 16, 64);
        acc[i] += __shfl_xor(acc[i], 32, 64);
    }
    if (lane < 16) {
        float* op = rst + (size_t)n * 128 + cl * 8;
        nt_store4(op, acc[0], acc[1], acc[2], acc[3]);
        nt_store4(op + 4, acc[4], acc[5], acc[6], acc[7]);
    }
}

extern "C" void kernel_launch(void* const* d_in, const int* in_sizes, int n_in,
                              void* d_out, int out_size, void* d_ws, size_t ws_size,
                              hipStream_t stream) {
    const float* feat = (const float*)d_in[0];
    const float* W = (const float*)d_in[1];
    const float* emb = (const float*)d_in[2];
    const int* e_feat = (const int*)d_in[3];
    const int* src = (const int*)d_in[4];
    const int* dst = (const int*)d_in[5];
    int N = in_sizes[0] / 128;
    int E = in_sizes[3];
    int nbuk = (N + 511) >> 9;
    int nchunk = (E + 4095) / 4096;        // 391
    int gemmBlocks = (N + 127) / 128;      // 782
    int aggBlocks = (N + 3) / 4;           // 25000
    int attnBlocks = (E + 255) / 256;      // 6250

    char* ws = (char*)d_ws;
    size_t off = 0;
    auto alloc = [&](size_t bytes) {
        void* p = ws + off;
        off = (off + bytes + 255) & ~(size_t)255;
        return p;
    };
    unsigned short* ftb = (unsigned short*)alloc((size_t)N * 128 * 2);
    unsigned short* Wb = (unsigned short*)alloc((size_t)in_sizes[1] * 2);
    float* stats = (float*)alloc((size_t)N * 8 * 4);
    unsigned* deg = (unsigned*)alloc((size_t)N * 4);
    unsigned* offs = (unsigned*)alloc((size_t)N * 4);
    unsigned* csr = (unsigned*)alloc((size_t)E * 4);
    unsigned* csr2 = (unsigned*)alloc((size_t)E * 4);
    unsigned* gpart = (unsigned*)alloc((size_t)nchunk * 256 * 4);
    unsigned* gbase = (unsigned*)alloc(256 * 4);
    unsigned* gcur = (unsigned*)alloc(256 * 4);

    float* rst = (float*)d_out;
    float* ao = (float*)d_out + (size_t)N * 128;

    k_bcnt<<<nchunk, 256, 0, stream>>>(dst, gpart, E, W, Wb);
    k_bscan<<<1, 256, 0, stream>>>(gpart, nchunk, gbase, gcur);
    k_partgemm<<<nchunk + gemmBlocks, 256, 0, stream>>>(
        src, dst, e_feat, gcur, csr2, E, nbuk, feat, Wb, ftb, N);
    k_bsort2<<<nbuk, 256, 0, stream>>>(csr2, gbase, gcur, emb, csr, offs, deg, stats, N);
    k_aggattn<<<aggBlocks + attnBlocks, 256, 0, stream>>>(
        csr, offs, deg, stats, emb, (const uint4*)ftb, rst, N,
        e_feat, dst, ao, E);
}

// Round 14
// 167.114 us; speedup vs baseline: 1.0813x; 1.0813x over previous
//
#include <hip/hip_runtime.h>

// ---------------- constants for this problem ----------------
// N_NODES=100000, N_EDGES=1600000, IN_FEATS=128, H=4, D=32, HD=128, NUM_ETYPES=8, DROP_BLOCKS=4
// Bucket = 512 consecutive dst nodes (nbuk = ceil(N/512) = 196).
// csr2 entry: src[0:17) | etype[17:20) | (dst&511)[20:29)
// csr  entry: src[0:20) | etype[20:23)

typedef short short8 __attribute__((ext_vector_type(8)));
typedef unsigned short ushort8 __attribute__((ext_vector_type(8)));
typedef float f32x4 __attribute__((ext_vector_type(4)));

__device__ inline unsigned short f2bf(float x) {
    unsigned u = __builtin_bit_cast(unsigned, x);
    u += 0x7FFFu + ((u >> 16) & 1u);   // RNE
    return (unsigned short)(u >> 16);
}

__device__ inline short8 cvt8(float4 lo, float4 hi) {
    short8 t;
    t[0] = (short)f2bf(lo.x); t[1] = (short)f2bf(lo.y);
    t[2] = (short)f2bf(lo.z); t[3] = (short)f2bf(lo.w);
    t[4] = (short)f2bf(hi.x); t[5] = (short)f2bf(hi.y);
    t[6] = (short)f2bf(hi.z); t[7] = (short)f2bf(hi.w);
    return t;
}

__device__ inline void nt_store4(float* p, float a, float b, float c, float d) {
    f32x4 v = (f32x4){a, b, c, d};
    __builtin_nontemporal_store(v, (f32x4*)p);
}

// K1: per-chunk bucket histogram (non-atomic partials, no memset needed).
// Blocks 0..7 additionally convert W (16384 fp32) -> Wb bf16.
__global__ __launch_bounds__(256) void k_bcnt(const int* __restrict__ dst,
                                              unsigned* __restrict__ gpart, int E,
                                              const float* __restrict__ W,
                                              unsigned short* __restrict__ Wb) {
    __shared__ unsigned l[256];
    int tid = threadIdx.x;
    if (blockIdx.x < 8) {
        int i = blockIdx.x * 2048 + tid * 8;
        float4 lo = *(const float4*)(W + i);
        float4 hi = *(const float4*)(W + i + 4);
        *(ushort8*)(Wb + i) = __builtin_bit_cast(ushort8, cvt8(lo, hi));
    }
    l[tid] = 0;
    __syncthreads();
    int base = blockIdx.x * 4096;
#pragma unroll
    for (int j = 0; j < 16; ++j) {
        int e = base + j * 256 + tid;
        if (e < E) atomicAdd(&l[(unsigned)dst[e] >> 9], 1u);
    }
    __syncthreads();
    gpart[blockIdx.x * 256 + tid] = l[tid];
}

// K2: column-reduce partials + exclusive scan (single block)
__global__ __launch_bounds__(256) void k_bscan(const unsigned* __restrict__ gpart,
                                               int nchunk,
                                               unsigned* __restrict__ gbase,
                                               unsigned* __restrict__ gcur) {
    __shared__ unsigned s[256];
    int t = threadIdx.x;
    unsigned sum = 0;
    int r = 0;
    for (; r + 4 <= nchunk; r += 4) {
        unsigned a0 = gpart[(r + 0) * 256 + t];
        unsigned a1 = gpart[(r + 1) * 256 + t];
        unsigned a2 = gpart[(r + 2) * 256 + t];
        unsigned a3 = gpart[(r + 3) * 256 + t];
        sum += a0 + a1 + a2 + a3;
    }
    for (; r < nchunk; ++r) sum += gpart[r * 256 + t];
    unsigned orig = sum;
    s[t] = sum;
    __syncthreads();
    for (int of = 1; of < 256; of <<= 1) {
        unsigned v = (t >= of) ? s[t - of] : 0u;
        __syncthreads();
        s[t] += v;
        __syncthreads();
    }
    unsigned eb = s[t] - orig;
    gbase[t] = eb;
    gcur[t] = eb;
}

// K3 (FUSED, sequential ranges): blocks [0, gemmBlocks) = 64-row GEMM tiles;
// blocks [gemmBlocks, gemmBlocks+partBlocks) = LDS-staged partition.
__global__ __launch_bounds__(256) void k_partgemm(
        const int* __restrict__ src, const int* __restrict__ dst,
        const int* __restrict__ ef, unsigned* __restrict__ gcur,
        unsigned* __restrict__ csr2, int E, int nbuk, int gemmBlocks,
        const float* __restrict__ feat, const unsigned short* __restrict__ Wb,
        unsigned short* __restrict__ ftb, int N) {
    __shared__ unsigned short Sb[128 * 136];  // 34 KB union
    int tid = threadIdx.x;
    int bid = blockIdx.x;

    if (bid >= gemmBlocks) {
        // ---------------- partition path ----------------
        unsigned* lcnt = (unsigned*)Sb;
        unsigned* lbase = lcnt + 256;
        unsigned* lcur = lbase + 256;
        unsigned* gw2 = lcur + 256;
        unsigned* stp = gw2 + 256;
        unsigned short* stb = (unsigned short*)(stp + 4096);
        int rid = bid - gemmBlocks;
        lcnt[tid] = 0;
        __syncthreads();

        int cb = rid * 4096;
        int cc = E - cb; if (cc > 4096) cc = 4096;

        unsigned pay[16];
        unsigned short bk[16];
#pragma unroll
        for (int j = 0; j < 16; ++j) {
            int idx = j * 256 + tid;
            if (idx < cc) {
                int e = cb + idx;
                unsigned d = (unsigned)dst[e];
                pay[j] = (unsigned)src[e] | ((unsigned)ef[e] << 17) | ((d & 511u) << 20);
                bk[j] = (unsigned short)(d >> 9);
                atomicAdd(&lcnt[bk[j]], 1u);
            }
        }
        __syncthreads();
        lbase[tid] = lcnt[tid];
        __syncthreads();
        for (int of = 1; of < 256; of <<= 1) {
            unsigned v = (tid >= of) ? lbase[tid - of] : 0u;
            __syncthreads();
            lbase[tid] += v;
            __syncthreads();
        }
        unsigned eb = lbase[tid] - lcnt[tid];
        __syncthreads();
        lbase[tid] = eb;
        lcur[tid] = eb;
        __syncthreads();
#pragma unroll
        for (int j = 0; j < 16; ++j) {
            int idx = j * 256 + tid;
            if (idx < cc) {
                unsigned lpos = atomicAdd(&lcur[bk[j]], 1u);
                stp[lpos] = pay[j];
                stb[lpos] = bk[j];
            }
        }
        if (tid < nbuk && lcnt[tid]) gw2[tid] = atomicAdd(&gcur[tid], lcnt[tid]);
        __syncthreads();
#pragma unroll
        for (int j = 0; j < 16; ++j) {
            int i = j * 256 + tid;
            if (i < cc) {
                unsigned b = stb[i];
                csr2[gw2[b] + (i - lbase[b])] = stp[i];
            }
        }
        return;
    }

    // ---------------- GEMM path: 64-row tile, all A-loads upfront ----------
    int row0 = bid * 64;

    // stage Wb (bf16): 8 x ushort8, swizzled (byte ^= (row&7)<<4)
#pragma unroll
    for (int it = 0; it < 8; ++it) {
        int idx = it * 2048 + tid * 8;
        int r = idx >> 7, c = idx & 127;
        ushort8 v = *(const ushort8*)(Wb + idx);
        *(ushort8*)((char*)Sb + (((unsigned)(r * 256 + c * 2)) ^ (unsigned)((r & 7) << 4))) = v;
    }

    int wv = tid >> 6, lane = tid & 63;
    int rl = lane & 15;
    unsigned swz = (unsigned)((lane & 7) << 4);
    int kq = (lane >> 4) * 16;          // LDS byte offset of this lane's k-octet
    int ko = (lane >> 4) * 8;           // element offset of k-octet

    int ra = row0 + wv * 16 + rl;       // one row per thread
    int rc = ra < N - 1 ? ra : N - 1;   // clamp (garbage discarded at store)
    const float* ap = feat + (size_t)rc * 128 + ko;

    // all 8 independent float4 loads in flight before any use
    float4 f[8];
#pragma unroll
    for (int kk = 0; kk < 4; ++kk) {
        f[2 * kk]     = *(const float4*)(ap + kk * 32);
        f[2 * kk + 1] = *(const float4*)(ap + kk * 32 + 4);
    }
    __syncthreads();

    f32x4 acc[8];
#pragma unroll
    for (int jt = 0; jt < 8; ++jt) acc[jt] = (f32x4){0.f, 0.f, 0.f, 0.f};

    const char* Bb = (const char*)Sb;
#pragma unroll
    for (int kk = 0; kk < 4; ++kk) {
        short8 a = cvt8(f[2 * kk], f[2 * kk + 1]);
        int kb = kk * 64 + kq;
#pragma unroll
        for (int jt = 0; jt < 8; ++jt) {
            short8 bj = *(const short8*)(Bb + (((unsigned)((jt * 16 + rl) * 256 + kb)) ^ swz));
            acc[jt] = __builtin_amdgcn_mfma_f32_16x16x32_bf16(a, bj, acc[jt], 0, 0, 0);
        }
    }

    // epilogue via LDS (W region dead) -> wide contiguous stores
    __syncthreads();
#pragma unroll
    for (int jt = 0; jt < 8; ++jt) {
        int col = jt * 16 + rl;
        int rbase = wv * 16 + ((lane >> 4) << 2);
#pragma unroll
        for (int rg = 0; rg < 4; ++rg)
            Sb[(rbase + rg) * 136 + col] = f2bf(acc[jt][rg]);
    }
    __syncthreads();
#pragma unroll
    for (int g = 0; g < 4; ++g) {
        int rloc = g * 16 + (tid >> 4);
        int cc = (tid & 15) * 8;
        int gr = row0 + rloc;
        if (gr < N) {
            ushort8 v = *(const ushort8*)(&Sb[rloc * 136 + cc]);
            *(ushort8*)(ftb + (size_t)gr * 128 + cc) = v;
        }
    }
}

// K4: per-bucket: count (node,etype), scan node degrees -> offs/deg/stats,
// then counting-sort into final node-grouped CSR. gend[b] = bucket END index.
__global__ __launch_bounds__(256) void k_bsort2(const unsigned* __restrict__ csr2,
                                                const unsigned* __restrict__ gbase,
                                                const unsigned* __restrict__ gend,
                                                const float* __restrict__ emb,
                                                unsigned* __restrict__ csr,
                                                unsigned* __restrict__ offs,
                                                unsigned* __restrict__ deg,
                                                float* __restrict__ stats, int N) {
    __shared__ unsigned cnt8[512 * 8];   // 16 KB
    __shared__ unsigned degL[512];
    __shared__ unsigned offsL[512];
    __shared__ unsigned curL[512];
    __shared__ unsigned tmp[256];
    __shared__ float se[32];
    int b = blockIdx.x, tid = threadIdx.x;
    if (tid < 32) se[tid] = emb[tid];
#pragma unroll
    for (int i = 0; i < 16; ++i) cnt8[i * 256 + tid] = 0u;
    __syncthreads();
    unsigned r0 = gbase[b], r1 = gend[b];
    for (unsigned i = r0 + tid; i < r1; i += 256) {
        unsigned en = csr2[i];
        atomicAdd(&cnt8[((en >> 20) & 511u) * 8u + ((en >> 17) & 7u)], 1u);
    }
    __syncthreads();
    int n0 = tid * 2, n1 = tid * 2 + 1;
    unsigned d0 = 0, d1 = 0;
#pragma unroll
    for (int k = 0; k < 8; ++k) { d0 += cnt8[n0 * 8 + k]; d1 += cnt8[n1 * 8 + k]; }
    degL[n0] = d0; degL[n1] = d1;
    tmp[tid] = d0 + d1;
    __syncthreads();
    for (int of = 1; of < 256; of <<= 1) {
        unsigned v = (tid >= of) ? tmp[tid - of] : 0u;
        __syncthreads();
        tmp[tid] += v;
        __syncthreads();
    }
    unsigned eb = tmp[tid] - (d0 + d1);
    offsL[n0] = eb;        curL[n0] = eb;
    offsL[n1] = eb + d0;   curL[n1] = eb + d0;
#pragma unroll
    for (int q = 0; q < 2; ++q) {
        int nl = tid * 2 + q;
        int gn = b * 512 + nl;
        if (gn < N) {
            offs[gn] = r0 + offsL[nl];
            unsigned dg = degL[nl];
            deg[gn] = dg;
            const unsigned* c = &cnt8[nl * 8];
#pragma unroll
            for (int h = 0; h < 4; ++h) {
                float m = -3.4e38f;
#pragma unroll
                for (int tt = 0; tt < 8; ++tt)
                    if (c[tt]) m = fmaxf(m, se[tt * 4 + h]);
                float s = 0.f;
#pragma unroll
                for (int tt = 0; tt < 8; ++tt)
                    if (c[tt]) s += (float)c[tt] * expf(se[tt * 4 + h] - m);
                stats[(size_t)gn * 8 + h] = m;
                stats[(size_t)gn * 8 + 4 + h] = dg ? (1.0f / s) : 0.0f;
            }
        }
    }
    __syncthreads();
    for (unsigned i = r0 + tid; i < r1; i += 256) {
        unsigned en = csr2[i];
        unsigned nlo = (en >> 20) & 511u;
        unsigned tt = (en >> 17) & 7u;
        unsigned pos = r0 + atomicAdd(&curL[nlo], 1u);
        csr[pos] = (en & 0x1FFFFu) | (tt << 20);
    }
}

// K5 (FUSED, sequential): blocks [0, aggBlocks) = agg, 8 nodes/block
// (2 nodes per wave, sequential); rest = attn_out, 1024 edges/block.
__global__ __launch_bounds__(256) void k_aggattn(
        const unsigned* __restrict__ csr, const unsigned* __restrict__ offs,
        const unsigned* __restrict__ deg, const float* __restrict__ stats,
        const float* __restrict__ emb, const uint4* __restrict__ ft4,
        float* __restrict__ rst, int N, int aggBlocks,
        const int* __restrict__ e_feat, const int* __restrict__ dst,
        float* __restrict__ ao, int E) {
    __shared__ float sbuf[4 * 257];   // attn: 4*257; agg: 4 waves * 64
    int tid = threadIdx.x;
    int bid = blockIdx.x;

    if (bid >= aggBlocks) {
        // ---------------- attn_out path: 4 x 256 edges ----------------
        int rid = bid - aggBlocks;
        size_t lim = (size_t)E * 4;
#pragma unroll 1
        for (int r4 = 0; r4 < 4; ++r4) {
            int e = (rid * 4 + r4) * 256 + tid;
            float a0 = 0.f, a1 = 0.f, a2 = 0.f, a3 = 0.f;
            if (e < E) {
                int tt = e_feat[e];
                int d = dst[e];
                const float4* st4 = (const float4*)(stats + (size_t)d * 8);
                float4 m4 = st4[0], i4 = st4[1];
                float4 ee = *(const float4*)(emb + tt * 4);
                a0 = expf(ee.x - m4.x) * i4.x;
                a1 = expf(ee.y - m4.y) * i4.y;
                a2 = expf(ee.z - m4.z) * i4.z;
                a3 = expf(ee.w - m4.w) * i4.w;
            }
            __syncthreads();
            sbuf[0 * 257 + tid] = a0;
            sbuf[1 * 257 + tid] = a1;
            sbuf[2 * 257 + tid] = a2;
            sbuf[3 * 257 + tid] = a3;
            __syncthreads();
            size_t base = (size_t)(rid * 4 + r4) * 1024;   // float4 index
#pragma unroll
            for (int r = 0; r < 4; ++r) {
                size_t g = base + r * 256 + tid;
                if (g < lim) {
                    int gl = r * 256 + tid;
                    float v = sbuf[(gl & 3) * 257 + (gl >> 2)];
                    nt_store4(ao + g * 4, v, v, v, v);
                }
            }
        }
        return;
    }

    // ---------------- aggregate path: 2 nodes per wave ----------------
    float* wl = sbuf;
    int wv = tid >> 6, lane = tid & 63;
    int nbase = (bid * 4 + wv) * 2;
    // weights for both nodes of this wave: lane 0-31 -> node0, 32-63 -> node1
    {
        int nn = lane >> 5;
        int idx = lane & 31;
        int n = nbase + nn;
        if (n < N) {
            int tt = idx >> 2, hh = idx & 3;
            float m = stats[(size_t)n * 8 + hh];
            float is = stats[(size_t)n * 8 + 4 + hh];
            wl[wv * 64 + lane] = expf(emb[tt * 4 + hh] - m) * is;
        }
    }
    __syncthreads();
    int cl = lane & 15;
    int es = lane >> 4;
    int h = cl >> 2;

#pragma unroll 1
    for (int nn = 0; nn < 2; ++nn) {
        int n = __builtin_amdgcn_readfirstlane(nbase + nn);
        if (n >= N) break;
        unsigned o = offs[n], dg = deg[n];
        const float* wlh = wl + wv * 64 + nn * 32 + h;
        float acc[8];
#pragma unroll
        for (int i = 0; i < 8; ++i) acc[i] = 0.f;

        for (unsigned kb = 0; kb < dg; kb += 64) {
            unsigned rem = dg - kb; if (rem > 64) rem = 64;
            unsigned centry = 0;
            if (lane < (int)rem) centry = csr[o + kb + lane];
            unsigned g = 0;
            for (; g + 16 <= rem; g += 16) {
                uint4 f[4]; float a[4];
#pragma unroll
                for (int q = 0; q < 4; ++q) {
                    unsigned e = __shfl(centry, (int)(g + q * 4 + es), 64);
                    f[q] = ft4[(size_t)(e & 0xFFFFFu) * 16 + cl];
                    a[q] = wlh[(e >> 20) * 4];
                }
#pragma unroll
                for (int q = 0; q < 4; ++q) {
                    acc[0] = fmaf(a[q], __builtin_bit_cast(float, f[q].x << 16), acc[0]);
                    acc[1] = fmaf(a[q], __builtin_bit_cast(float, f[q].x & 0xFFFF0000u), acc[1]);
                    acc[2] = fmaf(a[q], __builtin_bit_cast(float, f[q].y << 16), acc[2]);
                    acc[3] = fmaf(a[q], __builtin_bit_cast(float, f[q].y & 0xFFFF0000u), acc[3]);
                    acc[4] = fmaf(a[q], __builtin_bit_cast(float, f[q].z << 16), acc[4]);
                    acc[5] = fmaf(a[q], __builtin_bit_cast(float, f[q].z & 0xFFFF0000u), acc[5]);
                    acc[6] = fmaf(a[q], __builtin_bit_cast(float, f[q].w << 16), acc[6]);
                    acc[7] = fmaf(a[q], __builtin_bit_cast(float, f[q].w & 0xFFFF0000u), acc[7]);
                }
            }
            for (; g < rem; g += 4) {
                int eidx = (int)g + es;
                bool valid = eidx < (int)rem;
                unsigned e = __shfl(centry, valid ? eidx : (int)g, 64);
                uint4 f = ft4[(size_t)(e & 0xFFFFFu) * 16 + cl];
                float a = valid ? wlh[(e >> 20) * 4] : 0.f;
                acc[0] = fmaf(a, __builtin_bit_cast(float, f.x << 16), acc[0]);
                acc[1] = fmaf(a, __builtin_bit_cast(float, f.x & 0xFFFF0000u), acc[1]);
                acc[2] = fmaf(a, __builtin_bit_cast(float, f.y << 16), acc[2]);
                acc[3] = fmaf(a, __builtin_bit_cast(float, f.y & 0xFFFF0000u), acc[3]);
                acc[4] = fmaf(a, __builtin_bit_cast(float, f.z << 16), acc[4]);
                acc[5] = fmaf(a, __builtin_bit_cast(float, f.z & 0xFFFF0000u), acc[5]);
                acc[6] = fmaf(a, __builtin_bit_cast(float, f.w << 16), acc[6]);
                acc[7] = fmaf(a, __builtin_bit_cast(float, f.w & 0xFFFF0000u), acc[7]);
            }
        }
#pragma unroll
        for (int i = 0; i < 8; ++i) {
            acc[i] += __shfl_xor(acc[i], 16, 64);
            acc[i] += __shfl_xor(acc[i], 32, 64);
        }
        if (lane < 16) {
            float* op = rst + (size_t)n * 128 + cl * 8;
            nt_store4(op, acc[0], acc[1], acc[2], acc[3]);
            nt_store4(op + 4, acc[4], acc[5], acc[6], acc[7]);
        }
    }
}

extern "C" void kernel_launch(void* const* d_in, const int* in_sizes, int n_in,
                              void* d_out, int out_size, void* d_ws, size_t ws_size,
                              hipStream_t stream) {
    const float* feat = (const float*)d_in[0];
    const float* W = (const float*)d_in[1];
    const float* emb = (const float*)d_in[2];
    const int* e_feat = (const int*)d_in[3];
    const int* src = (const int*)d_in[4];
    const int* dst = (const int*)d_in[5];
    int N = in_sizes[0] / 128;
    int E = in_sizes[3];
    int nbuk = (N + 511) >> 9;
    int nchunk = (E + 4095) / 4096;        // 391
    int gemmBlocks = (N + 63) / 64;        // 1563
    int aggBlocks = (N + 7) / 8;           // 12500
    int attnBlocks = (E + 1023) / 1024;    // 1563

    char* ws = (char*)d_ws;
    size_t off = 0;
    auto alloc = [&](size_t bytes) {
        void* p = ws + off;
        off = (off + bytes + 255) & ~(size_t)255;
        return p;
    };
    unsigned short* ftb = (unsigned short*)alloc((size_t)N * 128 * 2);
    unsigned short* Wb = (unsigned short*)alloc((size_t)in_sizes[1] * 2);
    float* stats = (float*)alloc((size_t)N * 8 * 4);
    unsigned* deg = (unsigned*)alloc((size_t)N * 4);
    unsigned* offs = (unsigned*)alloc((size_t)N * 4);
    unsigned* csr = (unsigned*)alloc((size_t)E * 4);
    unsigned* csr2 = (unsigned*)alloc((size_t)E * 4);
    unsigned* gpart = (unsigned*)alloc((size_t)nchunk * 256 * 4);
    unsigned* gbase = (unsigned*)alloc(256 * 4);
    unsigned* gcur = (unsigned*)alloc(256 * 4);

    float* rst = (float*)d_out;
    float* ao = (float*)d_out + (size_t)N * 128;

    k_bcnt<<<nchunk, 256, 0, stream>>>(dst, gpart, E, W, Wb);
    k_bscan<<<1, 256, 0, stream>>>(gpart, nchunk, gbase, gcur);
    k_partgemm<<<gemmBlocks + nchunk, 256, 0, stream>>>(
        src, dst, e_feat, gcur, csr2, E, nbuk, gemmBlocks, feat, Wb, ftb, N);
    k_bsort2<<<nbuk, 256, 0, stream>>>(csr2, gbase, gcur, emb, csr, offs, deg, stats, N);
    k_aggattn<<<aggBlocks + attnBlocks, 256, 0, stream>>>(
        csr, offs, deg, stats, emb, (const uint4*)ftb, rst, N, aggBlocks,
        e_feat, dst, ao, E);
}